// Round 1
// baseline (407.999 us; speedup 1.0000x reference)
//
#include <hip/hip_runtime.h>
#include <hip/hip_fp16.h>
#include <math.h>

// Problem constants
#define B_     4
#define CIN    128
#define LEN    2048
#define DMODEL 256
#define DSTATE 16
#define NHEADS 256
#define DINNER 768
#define CONVDIM 800      // DINNER + 2*DSTATE
#define DINPROJ 1824     // 2*DINNER + 2*DSTATE + NHEADS
#define EPS_   1e-5f
#define CHUNK  64
#define NCHUNK 32        // LEN / CHUNK

typedef _Float16 f16x8 __attribute__((ext_vector_type(8)));
typedef float    f32x4 __attribute__((ext_vector_type(4)));

__device__ __forceinline__ float silu_(float x){ return x / (1.0f + __expf(-x)); }
__device__ __forceinline__ float softplus_(float x){
    return x > 0.f ? x + log1pf(__expf(-x)) : log1pf(__expf(x));
}

// async global->LDS, 16B per lane; LDS dest = wave-uniform base + lane*16
__device__ __forceinline__ void gl2lds16(const _Float16* g, _Float16* l){
    __builtin_amdgcn_global_load_lds(
        (const __attribute__((address_space(1))) void*)g,
        (__attribute__((address_space(3))) void*)l, 16, 0, 0);
}

// ---------------------------------------------------------------------------
// fp32 -> fp16 convert (weights), grid-stride
// ---------------------------------------------------------------------------
__global__ __launch_bounds__(256) void k_f2h(const float* __restrict__ a,
                                             _Float16* __restrict__ o, int n){
    for (int i = blockIdx.x * 256 + threadIdx.x; i < n; i += gridDim.x * 256)
        o[i] = (_Float16)a[i];
}

// ---------------------------------------------------------------------------
// im2col for the conv projection: xcol[(b,l)][(ci,k)] = x[b,ci,l-1+k], fp16.
// ---------------------------------------------------------------------------
__global__ __launch_bounds__(256) void k_im2col(const float* __restrict__ x,
                                                _Float16* __restrict__ xcol){
    __shared__ float xs[CIN][68];      // 67 used
    int blk = blockIdx.x;              // 0..127
    int b  = blk >> 5;
    int l0 = (blk & 31) << 6;          // *64
    const float* xb = x + (size_t)b * CIN * LEN;
    for (int idx = threadIdx.x; idx < CIN * 67; idx += 256){
        int ci = idx / 67, j = idx % 67;
        int gl = l0 - 1 + j;
        xs[ci][j] = (gl >= 0 && gl < LEN) ? xb[ci * LEN + gl] : 0.f;
    }
    __syncthreads();
    #pragma unroll
    for (int v = 0; v < 16; v++){
        int id = v * 256 + threadIdx.x;   // 0..4095
        int rl = id >> 6, c = id & 63;    // row-in-tile, 16B chunk
        f16x8 pk;
        #pragma unroll
        for (int e = 0; e < 8; e++){
            int ci = c * 2 + (e >> 2), k = e & 3;
            pk[e] = (_Float16)xs[ci][rl + k];
        }
        *(f16x8*)&xcol[((size_t)(b * LEN + l0 + rl)) * 512 + c * 8] = pk;
    }
}

// ---------------------------------------------------------------------------
// Shared MFMA GEMM: C[M][N] = A[M][K] . Bw[N][K]^T, f16 inputs, fp32 acc.
// 128x128 tile, BK=32, 4 waves (2x2), each wave 4x4 mfma_f32_16x16x32_f16.
// ---------------------------------------------------------------------------
template<int K, int EPI>
__global__ __launch_bounds__(256) void k_gemm(const _Float16* __restrict__ A,
                                              const _Float16* __restrict__ Bw,
                                              const float* __restrict__ dt_bias,
                                              _Float16* __restrict__ o_u,
                                              _Float16* __restrict__ o_z,
                                              _Float16* __restrict__ o_xbc,
                                              _Float16* __restrict__ o_dt,
                                              float* __restrict__ o_f){
    __shared__ __align__(16) _Float16 As[128 * 32];
    __shared__ __align__(16) _Float16 Bs[128 * 32];
    int tid  = threadIdx.x;
    int wv   = tid >> 6;
    int lane = tid & 63;
    int quad = lane >> 4;
    int l16  = lane & 15;
    int m0 = blockIdx.x * 128;
    int n0 = blockIdx.y * 128;
    int wm = (wv >> 1) * 64;
    int wn = (wv & 1) * 64;
    int srow = lane >> 2;              // 0..15 staging row
    int scol = (lane & 3) * 8;         // halves offset 0,8,16,24

    f32x4 acc[4][4];
    #pragma unroll
    for (int i = 0; i < 4; i++)
        #pragma unroll
        for (int j = 0; j < 4; j++)
            acc[i][j] = (f32x4){0.f, 0.f, 0.f, 0.f};

    for (int k0 = 0; k0 < K; k0 += 32){
        #pragma unroll
        for (int j = 0; j < 2; j++){
            int ar = m0 + wv * 32 + j * 16 + srow;
            gl2lds16(A + (size_t)ar * K + k0 + scol,
                     &As[(wv * 32 + j * 16) * 32]);
            int nr = n0 + wv * 32 + j * 16 + srow;
            if (EPI == 1) nr = nr > (DINPROJ - 1) ? (DINPROJ - 1) : nr;
            gl2lds16(Bw + (size_t)nr * K + k0 + scol,
                     &Bs[(wv * 32 + j * 16) * 32]);
        }
        __syncthreads();               // vmcnt(0) drain before barrier
        f16x8 af[4], bf[4];
        #pragma unroll
        for (int i = 0; i < 4; i++)
            af[i] = *(const f16x8*)&As[(wm + i * 16 + l16) * 32 + quad * 8];
        #pragma unroll
        for (int j = 0; j < 4; j++)
            bf[j] = *(const f16x8*)&Bs[(wn + j * 16 + l16) * 32 + quad * 8];
        #pragma unroll
        for (int i = 0; i < 4; i++)
            #pragma unroll
            for (int j = 0; j < 4; j++)
                acc[i][j] = __builtin_amdgcn_mfma_f32_16x16x32_f16(
                                af[i], bf[j], acc[i][j], 0, 0, 0);
        __syncthreads();
    }

    if (EPI == 0){
        #pragma unroll
        for (int j = 0; j < 4; j++){
            int col = n0 + wn + j * 16 + l16;
            #pragma unroll
            for (int i = 0; i < 4; i++){
                int row = m0 + wm + i * 16 + quad * 4;
                #pragma unroll
                for (int r = 0; r < 4; r++)
                    o_u[(size_t)(row + r) * DMODEL + col] = (_Float16)acc[i][j][r];
            }
        }
    } else if (EPI == 1){
        #pragma unroll
        for (int j = 0; j < 4; j++){
            int col = n0 + wn + j * 16 + l16;
            if (col < DINNER){
                #pragma unroll
                for (int i = 0; i < 4; i++){
                    int row = m0 + wm + i * 16 + quad * 4;
                    #pragma unroll
                    for (int r = 0; r < 4; r++)
                        o_z[(size_t)(row + r) * DINNER + col] = (_Float16)acc[i][j][r];
                }
            } else if (col < DINNER + CONVDIM){
                int cc = col - DINNER;
                #pragma unroll
                for (int i = 0; i < 4; i++){
                    int row = m0 + wm + i * 16 + quad * 4;
                    #pragma unroll
                    for (int r = 0; r < 4; r++)
                        o_xbc[(size_t)(row + r) * CONVDIM + cc] = (_Float16)acc[i][j][r];
                }
            } else if (col < DINPROJ){
                int hh = col - (DINNER + CONVDIM);
                float bias = dt_bias[hh];
                #pragma unroll
                for (int i = 0; i < 4; i++){
                    int row = m0 + wm + i * 16 + quad * 4;
                    #pragma unroll
                    for (int r = 0; r < 4; r++)
                        o_dt[(size_t)(row + r) * NHEADS + hh] =
                            (_Float16)softplus_(acc[i][j][r] + bias);
                }
            }
        }
    } else {
        #pragma unroll
        for (int i = 0; i < 4; i++){
            int row = m0 + wm + i * 16 + quad * 4;
            int b = row >> 11, l = row & (LEN - 1);
            #pragma unroll
            for (int j = 0; j < 4; j++){
                int d = n0 + wn + j * 16 + l16;
                *(f32x4*)&o_f[(((size_t)(b * DMODEL + d)) << 11) + l] = acc[i][j];
            }
        }
    }
}

// ---------------------------------------------------------------------------
// depthwise causal conv (4-tap) + bias + SiLU, fp16 in/out.
// ---------------------------------------------------------------------------
__global__ __launch_bounds__(256) void k_dwconv(const __half* __restrict__ xbc,
                                                const float* __restrict__ cw,
                                                const float* __restrict__ cb,
                                                __half* __restrict__ xcc){
    int idx = blockIdx.x * 256 + threadIdx.x;   // < 8192*800
    int c = idx % CONVDIM;
    int r = idx / CONVDIM;
    int l = r & (LEN - 1);
    float4 wv = *(const float4*)(cw + c * 4);
    float acc = cb[c];
    if (l >= 3){
        const __half* base = xbc + (size_t)(r - 3) * CONVDIM + c;
        acc += __half2float(base[0]) * wv.x + __half2float(base[CONVDIM]) * wv.y +
               __half2float(base[2 * CONVDIM]) * wv.z + __half2float(base[3 * CONVDIM]) * wv.w;
    } else {
        const float wk[4] = {wv.x, wv.y, wv.z, wv.w};
        for (int k = 0; k < 4; k++){
            int t = l - 3 + k;
            if (t >= 0) acc += __half2float(xbc[(size_t)(r + k - 3) * CONVDIM + c]) * wk[k];
        }
    }
    xcc[idx] = __float2half(silu_(acc));
}

// ---------------------------------------------------------------------------
// FUSED scan pass A+Y: per (b, head-group-of-4, chunk): run the recurrence
// from ZERO state out of LDS-staged inputs, emitting
//   - y_local (incl. D_skip*x) directly to y
//   - chunk-final local state (fp16) and chunk decay exp(A*sum(dt))
// The contribution of the true chunk-initial state is added later by k_corr
// (linearity: y_t = y_local_t + exp(A*cum_t) * C_t . h_init).
// ---------------------------------------------------------------------------
__global__ __launch_bounds__(64) void k_scanAY(const __half* __restrict__ dtb,
                                               const __half* __restrict__ xcc,
                                               const float* __restrict__ A_log,
                                               const float* __restrict__ D_skip,
                                               __half* __restrict__ y,
                                               __half* __restrict__ cstate,
                                               float* __restrict__ dsum){
    __shared__ __align__(16) __half sBC[CHUNK * 32];   // [t][B0..15 C0..15]
    __shared__ __align__(8)  __half sx[CHUNK * 12];    // [t][4 heads x 3]
    __shared__ __align__(8)  __half sdt4[CHUNK * 4];   // [t][4 heads]
    int blk = blockIdx.x;              // 0..8191
    int c  = blk & (NCHUNK - 1);
    int hg = (blk >> 5) & 63;
    int b  = blk >> 11;
    int lane = threadIdx.x;
    int hl = lane >> 4;
    int n  = lane & 15;
    int h  = hg * 4 + hl;
    int t0 = c * CHUNK;
    size_t row0 = (size_t)(b * LEN + t0);

    // --- stage B/C rows: 4 x global_load_lds(16B); [64][32] halves, linear
    {
        const char* g = (const char*)xcc + (row0 * CONVDIM + DINNER) * 2;
        int tt = lane >> 2, q = lane & 3;
        #pragma unroll
        for (int i = 0; i < 4; i++)
            gl2lds16((const _Float16*)(g + (size_t)(i * 16 + tt) * (CONVDIM * 2) + q * 16),
                     (_Float16*)&sBC[i * 512]);
    }
    // --- stage x (24B/t, this head group) and dt (8B/t): one t per lane
    {
        const char* gx = (const char*)xcc + (row0 + lane) * (CONVDIM * 2) + hg * 24;
        uint2 a0 = *(const uint2*)(gx);
        uint2 a1 = *(const uint2*)(gx + 8);
        uint2 a2 = *(const uint2*)(gx + 16);
        *(uint2*)&sx[lane * 12]     = a0;
        *(uint2*)&sx[lane * 12 + 4] = a1;
        *(uint2*)&sx[lane * 12 + 8] = a2;
        const char* gd = (const char*)dtb + (row0 + lane) * (NHEADS * 2) + hg * 8;
        *(uint2*)&sdt4[lane * 4] = *(const uint2*)gd;
    }
    __syncthreads();

    float A   = -__expf(A_log[h]);
    float Dsk = D_skip[h];
    float h0 = 0.f, h1 = 0.f, h2 = 0.f, sdt = 0.f;
    __half* yp = y + row0 * DINNER + hg * 12 + hl * 3;
    #pragma unroll 4
    for (int t = 0; t < CHUNK; t++){
        float vx0 = __half2float(sx[t * 12 + hl * 3]);
        float vx1 = __half2float(sx[t * 12 + hl * 3 + 1]);
        float vx2 = __half2float(sx[t * 12 + hl * 3 + 2]);
        float vB  = __half2float(sBC[t * 32 + n]);
        float vC  = __half2float(sBC[t * 32 + 16 + n]);
        float cdt = __half2float(sdt4[t * 4 + hl]);
        float dA  = __expf(cdt * A);
        float dtB = cdt * vB;
        h0 = fmaf(h0, dA, vx0 * dtB);
        h1 = fmaf(h1, dA, vx1 * dtB);
        h2 = fmaf(h2, dA, vx2 * dtB);
        sdt += cdt;
        // reduce sum over n=0..15 for 3 values: 2 shared stages, select,
        // 2 more stages on disjoint lane sets (19 ops vs 24 full butterfly)
        float p0 = h0 * vC, p1 = h1 * vC, p2 = h2 * vC;
        p0 += __shfl_xor(p0, 1, 64); p1 += __shfl_xor(p1, 1, 64); p2 += __shfl_xor(p2, 1, 64);
        p0 += __shfl_xor(p0, 2, 64); p1 += __shfl_xor(p1, 2, 64); p2 += __shfl_xor(p2, 2, 64);
        int g = n & 3;
        float q = (g == 1) ? p1 : ((g == 2) ? p2 : p0);
        q += __shfl_xor(q, 4, 64);
        q += __shfl_xor(q, 8, 64);
        if (n < 3){
            float xv = (n == 0) ? vx0 : ((n == 1) ? vx1 : vx2);
            yp[n] = __float2half(fmaf(Dsk, xv, q));
        }
        yp += DINNER;
    }
    size_t sbase = (((size_t)(b * NHEADS + h)) * NCHUNK + c) * 48;
    cstate[sbase + n]      = __float2half(h0);
    cstate[sbase + 16 + n] = __float2half(h1);
    cstate[sbase + 32 + n] = __float2half(h2);
    if (n == 0) dsum[(size_t)(b * NHEADS + h) * NCHUNK + c] = __expf(A * sdt);
}

// ---------------------------------------------------------------------------
// scan pass B: per (b,h), combine chunk summaries sequentially; overwrite
// cstate[c] in place with the INITIAL state of chunk c.
// ---------------------------------------------------------------------------
__global__ __launch_bounds__(64) void k_scanB(__half* __restrict__ cstate,
                                              const float* __restrict__ dsum){
    int bh = blockIdx.x;               // 0..1023
    int lane = threadIdx.x;
    if (lane >= 48) return;
    __half* st = cstate + (size_t)bh * NCHUNK * 48 + lane;
    const float* dd = dsum + (size_t)bh * NCHUNK;
    float H = 0.f;
    for (int c = 0; c < NCHUNK; c++){
        float d = dd[c];
        float s = __half2float(st[(size_t)c * 48]);
        st[(size_t)c * 48] = __float2half(H);
        H = fmaf(H, d, s);
    }
}

// ---------------------------------------------------------------------------
// correction pass: y_t += exp(A*cum_t) * C_t . h_init  (fully parallel in t;
// cum_t = inclusive prefix of dt within chunk via 64-lane shfl scan).
// Chunk 0 has h_init = 0 -> skipped (grid.x = NCHUNK-1).
// ---------------------------------------------------------------------------
__global__ __launch_bounds__(64) void k_corr(const __half* __restrict__ dtb,
                                             const __half* __restrict__ xcc,
                                             const float* __restrict__ A_log,
                                             const __half* __restrict__ cstate,
                                             __half* __restrict__ y){
    __shared__ float sH[48];
    int c = 1 + blockIdx.x;            // 1..31
    int h = blockIdx.y;
    int b = blockIdx.z;
    int lane = threadIdx.x;            // = t within chunk
    size_t sbase = (((size_t)(b * NHEADS + h)) * NCHUNK + c) * 48;
    if (lane < 48) sH[lane] = __half2float(cstate[sbase + lane]);
    float A = -__expf(A_log[h]);
    int t0 = c * CHUNK;
    size_t row = (size_t)(b * LEN + t0 + lane);
    float cdt = __half2float(dtb[row * NHEADS + h]);
    float cum = cdt;
    #pragma unroll
    for (int m = 1; m < 64; m <<= 1){
        float v = __shfl_up(cum, m, 64);
        if (lane >= m) cum += v;
    }
    float decay = __expf(A * cum);
    __syncthreads();
    const __half* Cp = xcc + row * CONVDIM + DINNER + DSTATE;
    float c0 = 0.f, c1 = 0.f, c2 = 0.f;
    #pragma unroll
    for (int nn = 0; nn < 16; nn++){
        float cv = __half2float(Cp[nn]);
        c0 = fmaf(cv, sH[nn],      c0);
        c1 = fmaf(cv, sH[16 + nn], c1);
        c2 = fmaf(cv, sH[32 + nn], c2);
    }
    __half* yy = y + row * DINNER + h * 3;
    yy[0] = __float2half(fmaf(decay, c0, __half2float(yy[0])));
    yy[1] = __float2half(fmaf(decay, c1, __half2float(yy[1])));
    yy[2] = __float2half(fmaf(decay, c2, __half2float(yy[2])));
}

// ---------------------------------------------------------------------------
// gated RMSNorm (in place on y, fp16 storage, fp32 math)
// ---------------------------------------------------------------------------
__global__ __launch_bounds__(256) void k_norm(__half* __restrict__ y,
                                              const __half* __restrict__ z,
                                              const float* __restrict__ nw){
    __shared__ float wsum[4];
    size_t r = blockIdx.x;
    int tid = threadIdx.x;
    const __half* zr = z + r * DINNER;
    __half* yr = y + r * DINNER;
    int e0 = tid, e1 = tid + 256, e2 = tid + 512;
    float t0 = __half2float(yr[e0]) * silu_(__half2float(zr[e0]));
    float t1 = __half2float(yr[e1]) * silu_(__half2float(zr[e1]));
    float t2 = __half2float(yr[e2]) * silu_(__half2float(zr[e2]));
    float ss = t0 * t0 + t1 * t1 + t2 * t2;
    #pragma unroll
    for (int m = 1; m < 64; m <<= 1) ss += __shfl_xor(ss, m, 64);
    if ((tid & 63) == 0) wsum[tid >> 6] = ss;
    __syncthreads();
    float tot = wsum[0] + wsum[1] + wsum[2] + wsum[3];
    float sc = rsqrtf(tot / (float)DINNER + EPS_);
    yr[e0] = __float2half(t0 * sc * nw[e0]);
    yr[e1] = __float2half(t1 * sc * nw[e1]);
    yr[e2] = __float2half(t2 * sc * nw[e2]);
}

// ---------------------------------------------------------------------------
extern "C" void kernel_launch(void* const* d_in, const int* in_sizes, int n_in,
                              void* d_out, int out_size, void* d_ws, size_t ws_size,
                              hipStream_t stream) {
    const float* x          = (const float*)d_in[0];
    const float* proj_w     = (const float*)d_in[1];
    const float* in_proj_w  = (const float*)d_in[2];
    const float* conv_w     = (const float*)d_in[3];
    const float* conv_b     = (const float*)d_in[4];
    const float* dt_bias    = (const float*)d_in[5];
    const float* A_log      = (const float*)d_in[6];
    const float* D_skip     = (const float*)d_in[7];
    const float* norm_w     = (const float*)d_in[8];
    const float* out_proj_w = (const float*)d_in[9];
    float* out = (float*)d_out;

    // fp16 proj/in_proj weights live in d_out (dead until k_gemm<768,2>
    // overwrites all of d_out with the final result).
    char* ob = (char*)d_out;
    _Float16* pw_h  = (_Float16*)ob;                   //   262,144 B (256x512)
    _Float16* ipw_h = (_Float16*)(ob + 262144);        //   933,888 B (1824x256)

    char* wsb = (char*)d_ws;
    _Float16* xcol  = (_Float16*)(wsb);                // 8192x512 fp16
    _Float16* u_h   = (_Float16*)(wsb + 8388608);      // 8192x256 fp16
    __half*   xcc_h = (__half*)(wsb);                  // 8192x800 fp16 (alias)
    __half*   z_h   = (__half*)(wsb + 13107200);       // 8192x768
    __half*   xbc_h = (__half*)(wsb + 25690112);       // 8192x800
    __half*   y_h   = xbc_h;                           // alias: xbc dead after dwconv
    __half*   dt_h  = (__half*)(wsb + 38797312);       // 8192x256
    __half*   cstate= (__half*)(wsb + 42991616);       // B*NH*NCHUNK*48
    float*    dsum  = (float*)(wsb + 46137344);        // B*NH*NCHUNK
    _Float16* opw_h = (_Float16*)(wsb + 46268416);     // 256x768 fp16

    k_f2h   <<<64, 256, 0, stream>>>(proj_w,     pw_h,  DMODEL * CIN * 4);
    k_f2h   <<<64, 256, 0, stream>>>(in_proj_w,  ipw_h, DINPROJ * DMODEL);
    k_f2h   <<<64, 256, 0, stream>>>(out_proj_w, opw_h, DMODEL * DINNER);
    k_im2col<<<128, 256, 0, stream>>>(x, xcol);
    k_gemm<512, 0><<<dim3(64, 2), 256, 0, stream>>>(xcol, pw_h, nullptr,
        u_h, nullptr, nullptr, nullptr, nullptr);
    k_gemm<256, 1><<<dim3(64, 15), 256, 0, stream>>>(u_h, ipw_h, dt_bias,
        nullptr, (_Float16*)z_h, (_Float16*)xbc_h, (_Float16*)dt_h, nullptr);
    k_dwconv<<<25600, 256, 0, stream>>>(xbc_h, conv_w, conv_b, xcc_h);
    k_scanAY<<<8192, 64, 0, stream>>>(dt_h, xcc_h, A_log, D_skip, y_h, cstate, dsum);
    k_scanB <<<1024, 64, 0, stream>>>(cstate, dsum);
    k_corr  <<<dim3(NCHUNK - 1, NHEADS, B_), 64, 0, stream>>>(dt_h, xcc_h, A_log, cstate, y_h);
    k_norm  <<<8192, 256, 0, stream>>>(y_h, z_h, norm_w);
    k_gemm<768, 2><<<dim3(64, 2), 256, 0, stream>>>((const _Float16*)y_h, opw_h,
        nullptr, nullptr, nullptr, nullptr, nullptr, out);
}

// Round 2
// 295.019 us; speedup vs baseline: 1.3830x; 1.3830x over previous
//
#include <hip/hip_runtime.h>
#include <hip/hip_fp16.h>
#include <math.h>

// Problem constants
#define B_     4
#define CIN    128
#define LEN    2048
#define DMODEL 256
#define DSTATE 16
#define NHEADS 256
#define DINNER 768
#define CONVDIM 800      // DINNER + 2*DSTATE
#define DINPROJ 1824     // 2*DINNER + 2*DSTATE + NHEADS
#define EPS_   1e-5f
#define BAND   64        // rows staged per k_y block
#define NBAND  32        // LEN / BAND
#define SEG    16        // intra-band segment for pairwise scan

typedef _Float16 f16x8 __attribute__((ext_vector_type(8)));
typedef _Float16 f16x4 __attribute__((ext_vector_type(4)));
typedef float    f32x4 __attribute__((ext_vector_type(4)));

__device__ __forceinline__ float silu_(float x){ return x / (1.0f + __expf(-x)); }
__device__ __forceinline__ float softplus_(float x){
    return x > 0.f ? x + log1pf(__expf(-x)) : log1pf(__expf(x));
}

// async global->LDS, 16B per lane; LDS dest = wave-uniform base + lane*16
__device__ __forceinline__ void gl2lds16(const _Float16* g, _Float16* l){
    __builtin_amdgcn_global_load_lds(
        (const __attribute__((address_space(1))) void*)g,
        (__attribute__((address_space(3))) void*)l, 16, 0, 0);
}

// ---------------------------------------------------------------------------
// fp32 -> fp16 convert (weights), grid-stride
// ---------------------------------------------------------------------------
__global__ __launch_bounds__(256) void k_f2h(const float* __restrict__ a,
                                             _Float16* __restrict__ o, int n){
    for (int i = blockIdx.x * 256 + threadIdx.x; i < n; i += gridDim.x * 256)
        o[i] = (_Float16)a[i];
}

// ---------------------------------------------------------------------------
// im2col for the conv projection: xcol[(b,l)][(ci,k)] = x[b,ci,l-1+k], fp16.
// ---------------------------------------------------------------------------
__global__ __launch_bounds__(256) void k_im2col(const float* __restrict__ x,
                                                _Float16* __restrict__ xcol){
    __shared__ float xs[CIN][68];      // 67 used
    int blk = blockIdx.x;              // 0..127
    int b  = blk >> 5;
    int l0 = (blk & 31) << 6;          // *64
    const float* xb = x + (size_t)b * CIN * LEN;
    for (int idx = threadIdx.x; idx < CIN * 67; idx += 256){
        int ci = idx / 67, j = idx % 67;
        int gl = l0 - 1 + j;
        xs[ci][j] = (gl >= 0 && gl < LEN) ? xb[ci * LEN + gl] : 0.f;
    }
    __syncthreads();
    #pragma unroll
    for (int v = 0; v < 16; v++){
        int id = v * 256 + threadIdx.x;   // 0..4095
        int rl = id >> 6, c = id & 63;    // row-in-tile, 16B chunk
        f16x8 pk;
        #pragma unroll
        for (int e = 0; e < 8; e++){
            int ci = c * 2 + (e >> 2), k = e & 3;
            pk[e] = (_Float16)xs[ci][rl + k];
        }
        *(f16x8*)&xcol[((size_t)(b * LEN + l0 + rl)) * 512 + c * 8] = pk;
    }
}

// ---------------------------------------------------------------------------
// Shared MFMA GEMM: C[M][N] = A[M][K] . Bw[N][K]^T, f16 inputs, fp32 acc.
// ---------------------------------------------------------------------------
template<int K, int EPI>
__global__ __launch_bounds__(256) void k_gemm(const _Float16* __restrict__ A,
                                              const _Float16* __restrict__ Bw,
                                              const float* __restrict__ dt_bias,
                                              _Float16* __restrict__ o_u,
                                              _Float16* __restrict__ o_z,
                                              _Float16* __restrict__ o_xbc,
                                              _Float16* __restrict__ o_dt,
                                              float* __restrict__ o_f){
    __shared__ __align__(16) _Float16 As[128 * 32];
    __shared__ __align__(16) _Float16 Bs[128 * 32];
    int tid  = threadIdx.x;
    int wv   = tid >> 6;
    int lane = tid & 63;
    int quad = lane >> 4;
    int l16  = lane & 15;
    int m0 = blockIdx.x * 128;
    int n0 = blockIdx.y * 128;
    int wm = (wv >> 1) * 64;
    int wn = (wv & 1) * 64;
    int srow = lane >> 2;              // 0..15 staging row
    int scol = (lane & 3) * 8;         // halves offset 0,8,16,24

    f32x4 acc[4][4];
    #pragma unroll
    for (int i = 0; i < 4; i++)
        #pragma unroll
        for (int j = 0; j < 4; j++)
            acc[i][j] = (f32x4){0.f, 0.f, 0.f, 0.f};

    for (int k0 = 0; k0 < K; k0 += 32){
        #pragma unroll
        for (int j = 0; j < 2; j++){
            int ar = m0 + wv * 32 + j * 16 + srow;
            gl2lds16(A + (size_t)ar * K + k0 + scol,
                     &As[(wv * 32 + j * 16) * 32]);
            int nr = n0 + wv * 32 + j * 16 + srow;
            if (EPI == 1) nr = nr > (DINPROJ - 1) ? (DINPROJ - 1) : nr;
            gl2lds16(Bw + (size_t)nr * K + k0 + scol,
                     &Bs[(wv * 32 + j * 16) * 32]);
        }
        __syncthreads();               // vmcnt(0) drain before barrier
        f16x8 af[4], bf[4];
        #pragma unroll
        for (int i = 0; i < 4; i++)
            af[i] = *(const f16x8*)&As[(wm + i * 16 + l16) * 32 + quad * 8];
        #pragma unroll
        for (int j = 0; j < 4; j++)
            bf[j] = *(const f16x8*)&Bs[(wn + j * 16 + l16) * 32 + quad * 8];
        #pragma unroll
        for (int i = 0; i < 4; i++)
            #pragma unroll
            for (int j = 0; j < 4; j++)
                acc[i][j] = __builtin_amdgcn_mfma_f32_16x16x32_f16(
                                af[i], bf[j], acc[i][j], 0, 0, 0);
        __syncthreads();
    }

    if (EPI == 0){
        #pragma unroll
        for (int j = 0; j < 4; j++){
            int col = n0 + wn + j * 16 + l16;
            #pragma unroll
            for (int i = 0; i < 4; i++){
                int row = m0 + wm + i * 16 + quad * 4;
                #pragma unroll
                for (int r = 0; r < 4; r++)
                    o_u[(size_t)(row + r) * DMODEL + col] = (_Float16)acc[i][j][r];
            }
        }
    } else if (EPI == 1){
        #pragma unroll
        for (int j = 0; j < 4; j++){
            int col = n0 + wn + j * 16 + l16;
            if (col < DINNER){
                #pragma unroll
                for (int i = 0; i < 4; i++){
                    int row = m0 + wm + i * 16 + quad * 4;
                    #pragma unroll
                    for (int r = 0; r < 4; r++)
                        o_z[(size_t)(row + r) * DINNER + col] = (_Float16)acc[i][j][r];
                }
            } else if (col < DINNER + CONVDIM){
                int cc = col - DINNER;
                #pragma unroll
                for (int i = 0; i < 4; i++){
                    int row = m0 + wm + i * 16 + quad * 4;
                    #pragma unroll
                    for (int r = 0; r < 4; r++)
                        o_xbc[(size_t)(row + r) * CONVDIM + cc] = (_Float16)acc[i][j][r];
                }
            } else if (col < DINPROJ){
                int hh = col - (DINNER + CONVDIM);
                float bias = dt_bias[hh];
                #pragma unroll
                for (int i = 0; i < 4; i++){
                    int row = m0 + wm + i * 16 + quad * 4;
                    #pragma unroll
                    for (int r = 0; r < 4; r++)
                        o_dt[(size_t)(row + r) * NHEADS + hh] =
                            (_Float16)softplus_(acc[i][j][r] + bias);
                }
            }
        }
    } else {
        #pragma unroll
        for (int i = 0; i < 4; i++){
            int row = m0 + wm + i * 16 + quad * 4;
            int b = row >> 11, l = row & (LEN - 1);
            #pragma unroll
            for (int j = 0; j < 4; j++){
                int d = n0 + wn + j * 16 + l16;
                *(f32x4*)&o_f[(((size_t)(b * DMODEL + d)) << 11) + l] = acc[i][j];
            }
        }
    }
}

// ---------------------------------------------------------------------------
// depthwise causal conv (4-tap) + bias + SiLU, fp16 in/out.
// ---------------------------------------------------------------------------
__global__ __launch_bounds__(256) void k_dwconv(const __half* __restrict__ xbc,
                                                const float* __restrict__ cw,
                                                const float* __restrict__ cb,
                                                __half* __restrict__ xcc){
    int idx = blockIdx.x * 256 + threadIdx.x;   // < 8192*800
    int c = idx % CONVDIM;
    int r = idx / CONVDIM;
    int l = r & (LEN - 1);
    float4 wv = *(const float4*)(cw + c * 4);
    float acc = cb[c];
    if (l >= 3){
        const __half* base = xbc + (size_t)(r - 3) * CONVDIM + c;
        acc += __half2float(base[0]) * wv.x + __half2float(base[CONVDIM]) * wv.y +
               __half2float(base[2 * CONVDIM]) * wv.z + __half2float(base[3 * CONVDIM]) * wv.w;
    } else {
        const float wk[4] = {wv.x, wv.y, wv.z, wv.w};
        for (int k = 0; k < 4; k++){
            int t = l - 3 + k;
            if (t >= 0) acc += __half2float(xbc[(size_t)(r + k - 3) * CONVDIM + c]) * wk[k];
        }
    }
    xcc[idx] = __float2half(silu_(acc));
}

// ---------------------------------------------------------------------------
// k_y: chunked-SSD scan. One block per (band of 64 rows, head-quarter, b).
// Since ngroups==1, G[t][s] = C_t.B_s is shared across all heads.
// Within 16-row segments, y is a masked pairwise sum (all exps of <=0 args);
// segment-boundary states chain in-register inside the band. Emits:
//   y (band-local, fp16), E0 = exp(A*cum_t) fp32, per-band final state
//   (cstate fp16) and band decay (dsum).
// ---------------------------------------------------------------------------
__global__ __launch_bounds__(256) void k_y(const __half* __restrict__ dtb,
                                           const __half* __restrict__ xcc,
                                           const float* __restrict__ A_log,
                                           __half* __restrict__ y,
                                           float* __restrict__ E0,
                                           __half* __restrict__ cstate,
                                           float* __restrict__ dsum){
    // LDS layout (bytes):
    //   [0,4096)      sBC  [64][32]h   (B0..15 | C0..15)
    //   [4096,28672)  sX   [64][192]h  (x, premultiplied by dt after P0.5)
    //                 sHL  [3][64][48]h ALIAS over sX (written after P2)
    //   [28672,36864) sDT  [64][64]h
    //   [36864,54272) sA   [64][68]f   a[t][h] = A_h * cum_t[h]
    //   [54272,59392) sG   [64][20]f   G[t][ss], ss = s within segment
    __shared__ __align__(16) char smem[59392];
    __half* sBC = (__half*)smem;
    __half* sX  = (__half*)(smem + 4096);
    __half* sHL = (__half*)(smem + 4096);
    __half* sDT = (__half*)(smem + 28672);
    float*  sA  = (float*)(smem + 36864);
    float*  sG  = (float*)(smem + 54272);

    int band = blockIdx.x, hq = blockIdx.y, b = blockIdx.z;
    int row0 = band * BAND;
    int tid = threadIdx.x;
    int wv = tid >> 6, lane = tid & 63;

    // ---- P0: stage BC (4 calls), X (24), DT (8) -> 9 gl2lds16 per wave
    {
        int c = wv, slot = c * 64 + lane;
        int row = slot >> 2, off = slot & 3;
        gl2lds16((const _Float16*)((const char*)xcc +
                   (size_t)(b * LEN + row0 + row) * 1600 + 1536 + off * 16),
                 (_Float16*)(smem + c * 1024));
    }
    #pragma unroll
    for (int i = 0; i < 6; i++){
        int c = wv + i * 4, slot = c * 64 + lane;
        int row = slot / 24, off = slot % 24;
        gl2lds16((const _Float16*)((const char*)xcc +
                   (size_t)(b * LEN + row0 + row) * 1600 + hq * 384 + off * 16),
                 (_Float16*)(smem + 4096 + c * 1024));
    }
    #pragma unroll
    for (int i = 0; i < 2; i++){
        int c = wv + i * 4, slot = c * 64 + lane;
        int row = slot >> 3, off = slot & 7;
        gl2lds16((const _Float16*)((const char*)dtb +
                   (size_t)(b * LEN + row0 + row) * 512 + hq * 128 + off * 16),
                 (_Float16*)(smem + 28672 + c * 1024));
    }
    __syncthreads();

    // ---- P0.5: prefix a (threads 0..63) | G (64..127) | x *= dt (128..255)
    if (tid < 64){
        int h = tid;
        float A = -__expf(A_log[hq * 64 + h]);
        float cum = 0.f;
        for (int tt = 0; tt < 64; tt++){
            cum += (float)sDT[tt * 64 + h];
            sA[tt * 68 + h] = A * cum;
        }
    } else if (tid < 128){
        int base = tid - 64;
        #pragma unroll
        for (int i = 0; i < 16; i++){
            int e = base + i * 64;            // 0..1023
            int tt = e >> 4, ss = e & 15;
            int s = (tt & 48) + ss;
            f16x8 ca = *(const f16x8*)&sBC[tt * 32 + 16];
            f16x8 cb = *(const f16x8*)&sBC[tt * 32 + 24];
            f16x8 ba = *(const f16x8*)&sBC[s * 32];
            f16x8 bb = *(const f16x8*)&sBC[s * 32 + 8];
            float acc = 0.f;
            #pragma unroll
            for (int n = 0; n < 8; n++)
                acc += (float)ca[n] * (float)ba[n] + (float)cb[n] * (float)bb[n];
            sG[tt * 20 + ss] = acc;
        }
    } else {
        int base = tid - 128;
        #pragma unroll
        for (int i = 0; i < 32; i++){
            int p = base + i * 128;           // 0..4095
            int tt = p >> 6, h = p & 63;
            float dtv = (float)sDT[tt * 64 + h];
            int xi = tt * 192 + h * 3;
            sX[xi]     = __float2half((float)sX[xi]     * dtv);
            sX[xi + 1] = __float2half((float)sX[xi + 1] * dtv);
            sX[xi + 2] = __float2half((float)sX[xi + 2] * dtv);
        }
    }
    __syncthreads();

    // ---- P1: per-thread (t, 16 heads): masked within-segment pair sum
    int t = tid >> 2, hsub = tid & 3, Hb = hsub * 16;
    int tmod = t & 15, tseg = t & 48;

    f32x4 atv[4];
    #pragma unroll
    for (int k4 = 0; k4 < 4; k4++)
        atv[k4] = *(const f32x4*)&sA[t * 68 + Hb + k4 * 4];

    {   // E0 = exp(a_t) fp32
        float* E0p = E0 + ((size_t)(b * LEN + row0 + t)) * 256 + hq * 64 + Hb;
        #pragma unroll
        for (int k4 = 0; k4 < 4; k4++){
            f32x4 ev;
            #pragma unroll
            for (int j = 0; j < 4; j++) ev[j] = __expf(atv[k4][j]);
            *(f32x4*)&E0p[k4 * 4] = ev;
        }
    }

    float y0[16], y1[16], y2[16];
    #pragma unroll
    for (int i = 0; i < 16; i++){ y0[i] = 0.f; y1[i] = 0.f; y2[i] = 0.f; }

    for (int ss = 0; ss < 16; ss++){
        int s = tseg + ss;
        float g = sG[t * 20 + ss];
        bool valid = (ss <= tmod);
        f32x4 av[4];
        #pragma unroll
        for (int k4 = 0; k4 < 4; k4++)
            av[k4] = *(const f32x4*)&sA[s * 68 + Hb + k4 * 4];
        f16x8 xv[6];
        #pragma unroll
        for (int c = 0; c < 6; c++)
            xv[c] = *(const f16x8*)&sX[s * 192 + Hb * 3 + c * 8];
        #pragma unroll
        for (int k4 = 0; k4 < 4; k4++)
            #pragma unroll
            for (int j = 0; j < 4; j++){
                int hh = k4 * 4 + j;
                float d = fminf(atv[k4][j] - av[k4][j], 0.f);
                float w = __expf(d) * g;
                w = valid ? w : 0.f;
                y0[hh] = fmaf(w, (float)xv[(hh*3+0)>>3][(hh*3+0)&7], y0[hh]);
                y1[hh] = fmaf(w, (float)xv[(hh*3+1)>>3][(hh*3+1)&7], y1[hh]);
                y2[hh] = fmaf(w, (float)xv[(hh*3+2)>>3][(hh*3+2)&7], y2[hh]);
            }
    }

    // ---- P2: per-thread (h, n-quad): segment-local final states
    int h2 = tid >> 2, ng = tid & 3;
    float F[4][12];
    float aeK[4];
    #pragma unroll
    for (int k = 0; k < 4; k++){
        float ae = sA[(k * 16 + 15) * 68 + h2];
        aeK[k] = ae;
        #pragma unroll
        for (int i = 0; i < 12; i++) F[k][i] = 0.f;
        for (int ss = 0; ss < 16; ss++){
            int s = k * 16 + ss;
            float e = __expf(ae - sA[s * 68 + h2]);
            f16x4 bv = *(const f16x4*)&sBC[s * 32 + ng * 4];
            float x0 = (float)sX[s * 192 + h2 * 3];
            float x1 = (float)sX[s * 192 + h2 * 3 + 1];
            float x2 = (float)sX[s * 192 + h2 * 3 + 2];
            #pragma unroll
            for (int nn = 0; nn < 4; nn++){
                float wb = e * (float)bv[nn];
                F[k][nn*3+0] = fmaf(wb, x0, F[k][nn*3+0]);
                F[k][nn*3+1] = fmaf(wb, x1, F[k][nn*3+1]);
                F[k][nn*3+2] = fmaf(wb, x2, F[k][nn*3+2]);
            }
        }
    }

    __syncthreads();   // all LDS reads of sX done before sHL overwrite

    // ---- P2b: chain boundary states; write sHL[0..2], cstate, dsum
    {
        float hc[12];
        #pragma unroll
        for (int i = 0; i < 12; i++) hc[i] = F[0][i];
        #pragma unroll
        for (int i = 0; i < 12; i++)
            sHL[(0 * 64 + h2) * 48 + ng * 12 + i] = __float2half(hc[i]);
        #pragma unroll
        for (int k = 1; k <= 2; k++){
            float D = __expf(aeK[k] - aeK[k-1]);
            #pragma unroll
            for (int i = 0; i < 12; i++) hc[i] = fmaf(D, hc[i], F[k][i]);
            #pragma unroll
            for (int i = 0; i < 12; i++)
                sHL[(k * 64 + h2) * 48 + ng * 12 + i] = __float2half(hc[i]);
        }
        float D3 = __expf(aeK[3] - aeK[2]);
        __half* cp = cstate + ((size_t)((b * 256 + hq * 64 + h2) * NBAND + band)) * 48 + ng * 12;
        #pragma unroll
        for (int i = 0; i < 12; i++)
            cp[i] = __float2half(fmaf(D3, hc[i], F[3][i]));
        if (ng == 0)
            dsum[(size_t)(b * 256 + hq * 64 + h2) * NBAND + band] = __expf(aeK[3]);
    }
    __syncthreads();

    // ---- P3: intra-band cross-segment terms + store y
    {
        f16x8 cva = *(const f16x8*)&sBC[t * 32 + 16];
        f16x8 cvb = *(const f16x8*)&sBC[t * 32 + 24];
        int k = t >> 4;
        if (k > 0){
            const float* arow = &sA[(k * 16 - 1) * 68];
            #pragma unroll
            for (int k4 = 0; k4 < 4; k4++)
                #pragma unroll
                for (int j = 0; j < 4; j++){
                    int hh = k4 * 4 + j, h = Hb + hh;
                    float e = __expf(atv[k4][j] - arow[h]);
                    const __half* hl = &sHL[((k - 1) * 64 + h) * 48];
                    f16x8 hv[6];
                    #pragma unroll
                    for (int c = 0; c < 6; c++) hv[c] = *(const f16x8*)&hl[c * 8];
                    float a0 = 0.f, a1 = 0.f, a2 = 0.f;
                    #pragma unroll
                    for (int n = 0; n < 16; n++){
                        float cn = (n < 8) ? (float)cva[n & 7] : (float)cvb[n & 7];
                        a0 = fmaf(cn, (float)hv[(n*3+0)>>3][(n*3+0)&7], a0);
                        a1 = fmaf(cn, (float)hv[(n*3+1)>>3][(n*3+1)&7], a1);
                        a2 = fmaf(cn, (float)hv[(n*3+2)>>3][(n*3+2)&7], a2);
                    }
                    y0[hh] = fmaf(e, a0, y0[hh]);
                    y1[hh] = fmaf(e, a1, y1[hh]);
                    y2[hh] = fmaf(e, a2, y2[hh]);
                }
        }
        __half* yp = y + (size_t)(b * LEN + row0 + t) * DINNER + hq * 192 + hsub * 48;
        #pragma unroll
        for (int c = 0; c < 6; c++){
            f16x8 pk;
            #pragma unroll
            for (int e2 = 0; e2 < 8; e2++){
                int gi = c * 8 + e2;
                int hh = gi / 3, p = gi % 3;
                pk[e2] = (_Float16)(p == 0 ? y0[hh] : (p == 1 ? y1[hh] : y2[hh]));
            }
            *(f16x8*)&yp[c * 8] = pk;
        }
    }
}

// ---------------------------------------------------------------------------
// scan pass B: per (b,h), combine band summaries sequentially; overwrite
// cstate[band] in place with the INITIAL state of that band.
// ---------------------------------------------------------------------------
__global__ __launch_bounds__(64) void k_scanB(__half* __restrict__ cstate,
                                              const float* __restrict__ dsum){
    int bh = blockIdx.x;               // 0..1023
    int lane = threadIdx.x;
    if (lane >= 48) return;
    __half* st = cstate + (size_t)bh * NBAND * 48 + lane;
    const float* dd = dsum + (size_t)bh * NBAND;
    float H = 0.f;
    for (int c = 0; c < NBAND; c++){
        float d = dd[c];
        float s = __half2float(st[(size_t)c * 48]);
        st[(size_t)c * 48] = __float2half(H);
        H = fmaf(H, d, s);
    }
}

// ---------------------------------------------------------------------------
// k_corr: y_t += E0_t * (C_t . h_band_init), fully staged & vectorized.
// One block per (band, head-quarter, b); band 0 adds zeros (h_init = 0).
// ---------------------------------------------------------------------------
__global__ __launch_bounds__(256) void k_corr(const float* __restrict__ E0,
                                              const __half* __restrict__ xcc,
                                              const __half* __restrict__ cstate,
                                              __half* __restrict__ y){
    // LDS: sC [64][16]h (2KB) | sHI [64][48]h (6KB) | sE0 [64][64]f (16KB)
    __shared__ __align__(16) char smem[24576];
    __half* sC  = (__half*)smem;
    __half* sHI = (__half*)(smem + 2048);
    float*  sE0 = (float*)(smem + 8192);

    int band = blockIdx.x, hq = blockIdx.y, b = blockIdx.z;
    int row0 = band * BAND;
    int tid = threadIdx.x;
    int wv = tid >> 6, lane = tid & 63;

    #pragma unroll
    for (int i = 0; i < 6; i++){
        int m = wv * 6 + i;            // 0..23
        if (m < 2){
            int slot = m * 64 + lane, row = slot >> 1, off = slot & 1;
            gl2lds16((const _Float16*)((const char*)xcc +
                       (size_t)(b * LEN + row0 + row) * 1600 + 1568 + off * 16),
                     (_Float16*)(smem + m * 1024));
        } else if (m < 8){
            int mm = m - 2, slot = mm * 64 + lane;
            int h = slot / 6, off = slot % 6;
            gl2lds16((const _Float16*)((const char*)cstate +
                       ((size_t)((b * 256 + hq * 64 + h) * NBAND + band)) * 96 + off * 16),
                     (_Float16*)(smem + 2048 + mm * 1024));
        } else {
            int mm = m - 8, slot = mm * 64 + lane;
            int row = slot >> 4, off = slot & 15;
            gl2lds16((const _Float16*)((const char*)E0 +
                       (size_t)(b * LEN + row0 + row) * 1024 + hq * 256 + off * 16),
                     (_Float16*)(smem + 8192 + mm * 1024));
        }
    }
    __syncthreads();

    int t = tid >> 2, hsub = tid & 3, Hb = hsub * 16;
    f16x8 cva = *(const f16x8*)&sC[t * 16];
    f16x8 cvb = *(const f16x8*)&sC[t * 16 + 8];
    f32x4 e0v[4];
    #pragma unroll
    for (int k4 = 0; k4 < 4; k4++)
        e0v[k4] = *(const f32x4*)&sE0[t * 64 + Hb + k4 * 4];

    __half* yp = y + (size_t)(b * LEN + row0 + t) * DINNER + hq * 192 + hsub * 48;
    f16x8 yv[6];
    #pragma unroll
    for (int c = 0; c < 6; c++) yv[c] = *(const f16x8*)&yp[c * 8];
    float o[48];
    #pragma unroll
    for (int c = 0; c < 6; c++)
        #pragma unroll
        for (int e2 = 0; e2 < 8; e2++) o[c * 8 + e2] = (float)yv[c][e2];

    #pragma unroll
    for (int k4 = 0; k4 < 4; k4++)
        #pragma unroll
        for (int j = 0; j < 4; j++){
            int hh = k4 * 4 + j, h = Hb + hh;
            const __half* hl = &sHI[h * 48];
            f16x8 hv[6];
            #pragma unroll
            for (int c = 0; c < 6; c++) hv[c] = *(const f16x8*)&hl[c * 8];
            float a0 = 0.f, a1 = 0.f, a2 = 0.f;
            #pragma unroll
            for (int n = 0; n < 16; n++){
                float cn = (n < 8) ? (float)cva[n & 7] : (float)cvb[n & 7];
                a0 = fmaf(cn, (float)hv[(n*3+0)>>3][(n*3+0)&7], a0);
                a1 = fmaf(cn, (float)hv[(n*3+1)>>3][(n*3+1)&7], a1);
                a2 = fmaf(cn, (float)hv[(n*3+2)>>3][(n*3+2)&7], a2);
            }
            float e0 = e0v[k4][j];
            o[hh*3+0] = fmaf(e0, a0, o[hh*3+0]);
            o[hh*3+1] = fmaf(e0, a1, o[hh*3+1]);
            o[hh*3+2] = fmaf(e0, a2, o[hh*3+2]);
        }

    #pragma unroll
    for (int c = 0; c < 6; c++){
        f16x8 pk;
        #pragma unroll
        for (int e2 = 0; e2 < 8; e2++) pk[e2] = (_Float16)o[c * 8 + e2];
        *(f16x8*)&yp[c * 8] = pk;
    }
}

// ---------------------------------------------------------------------------
// gated RMSNorm (in place on y, fp16 storage, fp32 math) + D_skip*x add
// ---------------------------------------------------------------------------
__global__ __launch_bounds__(256) void k_norm(__half* __restrict__ y,
                                              const __half* __restrict__ z,
                                              const __half* __restrict__ xcc,
                                              const float* __restrict__ D_skip,
                                              const float* __restrict__ nw){
    __shared__ float wsum[4];
    size_t r = blockIdx.x;
    int tid = threadIdx.x;
    const __half* zr = z + r * DINNER;
    const __half* xr = xcc + r * CONVDIM;
    __half* yr = y + r * DINNER;
    int e0 = tid, e1 = tid + 256, e2 = tid + 512;
    float t0 = (__half2float(yr[e0]) + D_skip[e0/3]*__half2float(xr[e0])) * silu_(__half2float(zr[e0]));
    float t1 = (__half2float(yr[e1]) + D_skip[e1/3]*__half2float(xr[e1])) * silu_(__half2float(zr[e1]));
    float t2 = (__half2float(yr[e2]) + D_skip[e2/3]*__half2float(xr[e2])) * silu_(__half2float(zr[e2]));
    float ss = t0 * t0 + t1 * t1 + t2 * t2;
    #pragma unroll
    for (int m = 1; m < 64; m <<= 1) ss += __shfl_xor(ss, m, 64);
    if ((tid & 63) == 0) wsum[tid >> 6] = ss;
    __syncthreads();
    float tot = wsum[0] + wsum[1] + wsum[2] + wsum[3];
    float sc = rsqrtf(tot / (float)DINNER + EPS_);
    yr[e0] = __float2half(t0 * sc * nw[e0]);
    yr[e1] = __float2half(t1 * sc * nw[e1]);
    yr[e2] = __float2half(t2 * sc * nw[e2]);
}

// ---------------------------------------------------------------------------
extern "C" void kernel_launch(void* const* d_in, const int* in_sizes, int n_in,
                              void* d_out, int out_size, void* d_ws, size_t ws_size,
                              hipStream_t stream) {
    const float* x          = (const float*)d_in[0];
    const float* proj_w     = (const float*)d_in[1];
    const float* in_proj_w  = (const float*)d_in[2];
    const float* conv_w     = (const float*)d_in[3];
    const float* conv_b     = (const float*)d_in[4];
    const float* dt_bias    = (const float*)d_in[5];
    const float* A_log      = (const float*)d_in[6];
    const float* D_skip     = (const float*)d_in[7];
    const float* norm_w     = (const float*)d_in[8];
    const float* out_proj_w = (const float*)d_in[9];
    float* out = (float*)d_out;

    // d_out (8 MB) triple-duty:
    //   1) fp16 proj/in_proj weights (dead after gemm<256,1>)
    //   2) E0 = exp(A*cum) fp32 [8192][256] (k_y..k_corr)
    //   3) final output (gemm<768,2> overwrites everything)
    char* ob = (char*)d_out;
    _Float16* pw_h  = (_Float16*)ob;                   //   262,144 B (256x512)
    _Float16* ipw_h = (_Float16*)(ob + 262144);        //   933,888 B (1824x256)
    float*    E0    = (float*)d_out;                   // 8,388,608 B exactly

    char* wsb = (char*)d_ws;
    _Float16* xcol  = (_Float16*)(wsb);                // 8192x512 fp16
    _Float16* u_h   = (_Float16*)(wsb + 8388608);      // 8192x256 fp16
    __half*   xcc_h = (__half*)(wsb);                  // 8192x800 fp16 (alias)
    __half*   z_h   = (__half*)(wsb + 13107200);       // 8192x768
    __half*   xbc_h = (__half*)(wsb + 25690112);       // 8192x800
    __half*   y_h   = xbc_h;                           // alias: xbc dead after dwconv
    __half*   dt_h  = (__half*)(wsb + 38797312);       // 8192x256
    __half*   cstate= (__half*)(wsb + 42991616);       // 1024*32*48 fp16 (3.1MB)
    float*    dsum  = (float*)(wsb + 46137344);        // 1024*32 f32
    _Float16* opw_h = (_Float16*)(wsb + 46268416);     // 256x768 fp16 -> total 46,661,632

    k_f2h   <<<64, 256, 0, stream>>>(proj_w,     pw_h,  DMODEL * CIN * 4);
    k_f2h   <<<64, 256, 0, stream>>>(in_proj_w,  ipw_h, DINPROJ * DMODEL);
    k_f2h   <<<64, 256, 0, stream>>>(out_proj_w, opw_h, DMODEL * DINNER);
    k_im2col<<<128, 256, 0, stream>>>(x, xcol);
    k_gemm<512, 0><<<dim3(64, 2), 256, 0, stream>>>(xcol, pw_h, nullptr,
        u_h, nullptr, nullptr, nullptr, nullptr);
    k_gemm<256, 1><<<dim3(64, 15), 256, 0, stream>>>(u_h, ipw_h, dt_bias,
        nullptr, (_Float16*)z_h, (_Float16*)xbc_h, (_Float16*)dt_h, nullptr);
    k_dwconv<<<25600, 256, 0, stream>>>(xbc_h, conv_w, conv_b, xcc_h);
    k_y     <<<dim3(NBAND, 4, B_), 256, 0, stream>>>(dt_h, xcc_h, A_log,
                                                     y_h, E0, cstate, dsum);
    k_scanB <<<1024, 64, 0, stream>>>(cstate, dsum);
    k_corr  <<<dim3(NBAND, 4, B_), 256, 0, stream>>>(E0, xcc_h, cstate, y_h);
    k_norm  <<<8192, 256, 0, stream>>>(y_h, z_h, xcc_h, D_skip, norm_w);
    k_gemm<768, 2><<<dim3(64, 2), 256, 0, stream>>>((const _Float16*)y_h, opw_h,
        nullptr, nullptr, nullptr, nullptr, nullptr, out);
}